// Round 5
// baseline (78.169 us; speedup 1.0000x reference)
//
#include <hip/hip_runtime.h>
#include <hip/hip_fp16.h>

#define LATENT 128
#define DQK    32
#define BB     4
#define NN     16384
#define KK     64
#define TOTAL_EDGES (BB * NN * KK)   // 4,194,304
#define TOTAL_NODES (BB * NN)        // 65,536
#define PAD    132                   // LDS row stride (floats)

typedef _Float16 half8 __attribute__((ext_vector_type(8)));
typedef float    f32x4 __attribute__((ext_vector_type(4)));

// ---------------------------------------------------------------------------
// Kernel 1: ks/qs = features @ W^T + b  (f16 out)
// LDS-tiled register-blocked GEMM (round-4 version, measured ~12 us).
// ---------------------------------------------------------------------------
__global__ __launch_bounds__(256, 2) void proj_kernel(
    const float* __restrict__ features,  // [B*N, 128]
    const float* __restrict__ Wk,        // [32, 128]
    const float* __restrict__ bk,        // [32]
    const float* __restrict__ Wq,        // [32, 128]
    const float* __restrict__ bq,        // [32]
    __half* __restrict__ ks,             // [B*N, 32] f16
    __half* __restrict__ qs)             // [B*N, 32] f16
{
    __shared__ float sf[64 * PAD];   // feature tile
    __shared__ float sw[64 * PAD];   // rows 0..31 = Wk, 32..63 = Wq
    __shared__ float sb[64];

    const int t = threadIdx.x;
    const int node0 = blockIdx.x * 64;

    #pragma unroll
    for (int j = 0; j < 8; ++j) {
        int idx = t + j * 256;
        int r = idx >> 5;
        int c = idx & 31;
        const float4* src = (r < 32) ? (const float4*)Wk : (const float4*)Wq;
        float4 v = src[(size_t)(r & 31) * 32 + c];
        *(float4*)&sw[r * PAD + c * 4] = v;
    }
    if (t < 64) sb[t] = (t < 32) ? bk[t] : bq[t - 32];

    #pragma unroll
    for (int j = 0; j < 8; ++j) {
        int idx = t + j * 256;
        int r = idx >> 5;
        int c = idx & 31;
        float4 v = ((const float4*)(features + (size_t)(node0 + r) * LATENT))[c];
        *(float4*)&sf[r * PAD + c * 4] = v;
    }
    __syncthreads();

    const int tx = t & 15;
    const int ty = t >> 4;

    float acc[4][4];
    #pragma unroll
    for (int i = 0; i < 4; ++i)
        #pragma unroll
        for (int u = 0; u < 4; ++u) acc[i][u] = 0.f;

    #pragma unroll 4
    for (int kk = 0; kk < 32; ++kk) {
        float4 a[4], b[4];
        #pragma unroll
        for (int i = 0; i < 4; ++i)
            a[i] = *(const float4*)&sf[(ty * 4 + i) * PAD + kk * 4];
        #pragma unroll
        for (int u = 0; u < 4; ++u)
            b[u] = *(const float4*)&sw[(tx + 16 * u) * PAD + kk * 4];
        #pragma unroll
        for (int i = 0; i < 4; ++i)
            #pragma unroll
            for (int u = 0; u < 4; ++u)
                acc[i][u] += a[i].x * b[u].x + a[i].y * b[u].y
                           + a[i].z * b[u].z + a[i].w * b[u].w;
    }

    #pragma unroll
    for (int u = 0; u < 4; ++u) {
        const int d = tx + 16 * u;
        const float bias = sb[d];
        __half* base = (d < 32) ? ks : qs;
        const int dd = d & 31;
        #pragma unroll
        for (int i = 0; i < 4; ++i) {
            const int node = node0 + ty * 4 + i;
            base[(size_t)node * DQK + dd] = __float2half(acc[i][u] + bias);
        }
    }
}

// ---------------------------------------------------------------------------
// Kernel 2: MFMA edge dots. Wave = 4 groups x 16 edges.
// Per group: gather kv as A-frag, qv as B-frag of mfma_f32_16x16x32_f16
// (lane: edge i = lane&15, k-chunk c = lane>>4, 8 f16 = 16 B per lane).
// C = Ks.Qs^T; wanted dots are the diagonal C[i][i], which is robust to any
// operand/layout transpose. C[i][i] sits at lane ((i>>2)<<4)|i, reg i&3.
// ---------------------------------------------------------------------------
__global__ __launch_bounds__(256) void edge_kernel(
    const int* __restrict__ xidx,     // indices[1] flat
    const int* __restrict__ yidx,     // indices[2] flat
    const __half* __restrict__ ks,    // [B*N, 32] f16
    const __half* __restrict__ qs,
    float* __restrict__ out)          // [B*N*K]
{
    const int lane = threadIdx.x & 63;
    const int wave = (blockIdx.x * 256 + threadIdx.x) >> 6;
    const int i = lane & 15;          // edge within group
    const int c = lane >> 4;          // k-chunk (8 f16)
    const int e_base = wave * 64;
    const int b = e_base >> 20;       // batch (uniform: 64-edge groups aligned)
    const int nodebase = b << 14;     // b * NN

    const _Float16* ksh = (const _Float16*)ks;
    const _Float16* qsh = (const _Float16*)qs;

    const bool writer = (c == (i >> 2));
    const int reg = i & 3;

    #pragma unroll
    for (int g = 0; g < 4; ++g) {
        const int e0 = e_base + g * 16;
        const int x = xidx[e0 + i];   // 16 dwords, broadcast x4: 1 line
        const int y = yidx[e0 + i];

        const half8 kv = *(const half8*)(ksh + (((size_t)(nodebase + x)) << 5) + (c << 3));
        const half8 qv = *(const half8*)(qsh + (((size_t)(nodebase + y)) << 5) + (c << 3));

        f32x4 acc = {0.f, 0.f, 0.f, 0.f};
        acc = __builtin_amdgcn_mfma_f32_16x16x32_f16(kv, qv, acc, 0, 0, 0);

        float v = acc[0];
        v = (reg == 1) ? acc[1] : v;
        v = (reg == 2) ? acc[2] : v;
        v = (reg == 3) ? acc[3] : v;

        if (writer) out[e0 + i] = v * 0.17677669529663687f;  // 32^-0.5
    }
}

// ---------------------------------------------------------------------------
extern "C" void kernel_launch(void* const* d_in, const int* in_sizes, int n_in,
                              void* d_out, int out_size, void* d_ws, size_t ws_size,
                              hipStream_t stream) {
    // Input order: indices, img, features, Wk, bk, Wq, bq
    const int*   indices  = (const int*)d_in[0];
    const float* features = (const float*)d_in[2];
    const float* Wk       = (const float*)d_in[3];
    const float* bk       = (const float*)d_in[4];
    const float* Wq       = (const float*)d_in[5];
    const float* bq       = (const float*)d_in[6];
    float* out = (float*)d_out;

    __half* ks = (__half*)d_ws;                       // [B*N, 32] f16
    __half* qs = ks + (size_t)TOTAL_NODES * DQK;

    const int* xidx = indices + (size_t)1 * TOTAL_EDGES;  // row 1 -> keys
    const int* yidx = indices + (size_t)2 * TOTAL_EDGES;  // row 2 -> queries

    proj_kernel<<<TOTAL_NODES / 64, 256, 0, stream>>>(features, Wk, bk, Wq, bq, ks, qs);
    // 256 edges per 256-thread block (4 waves x 64 edges)
    edge_kernel<<<TOTAL_EDGES / 256, 256, 0, stream>>>(xidx, yidx, ks, qs, out);
}

// Round 6
// 77.649 us; speedup vs baseline: 1.0067x; 1.0067x over previous
//
#include <hip/hip_runtime.h>
#include <hip/hip_fp16.h>

#define LATENT 128
#define DQK    32
#define BB     4
#define NN     16384
#define KK     64
#define TOTAL_EDGES (BB * NN * KK)   // 4,194,304
#define TOTAL_NODES (BB * NN)        // 65,536
#define PAD    132                   // LDS row stride (floats)
#define EG     8                     // edge groups (of 16) per wave

typedef _Float16 half8 __attribute__((ext_vector_type(8)));
typedef float    f32x4 __attribute__((ext_vector_type(4)));

// ---------------------------------------------------------------------------
// Kernel 1: ks/qs = features @ W^T + b  (f16 out)
// LDS-tiled register-blocked GEMM (round-4 version, measured ~12 us).
// ---------------------------------------------------------------------------
__global__ __launch_bounds__(256, 2) void proj_kernel(
    const float* __restrict__ features,  // [B*N, 128]
    const float* __restrict__ Wk,        // [32, 128]
    const float* __restrict__ bk,        // [32]
    const float* __restrict__ Wq,        // [32, 128]
    const float* __restrict__ bq,        // [32]
    __half* __restrict__ ks,             // [B*N, 32] f16
    __half* __restrict__ qs)             // [B*N, 32] f16
{
    __shared__ float sf[64 * PAD];
    __shared__ float sw[64 * PAD];
    __shared__ float sb[64];

    const int t = threadIdx.x;
    const int node0 = blockIdx.x * 64;

    #pragma unroll
    for (int j = 0; j < 8; ++j) {
        int idx = t + j * 256;
        int r = idx >> 5;
        int c = idx & 31;
        const float4* src = (r < 32) ? (const float4*)Wk : (const float4*)Wq;
        float4 v = src[(size_t)(r & 31) * 32 + c];
        *(float4*)&sw[r * PAD + c * 4] = v;
    }
    if (t < 64) sb[t] = (t < 32) ? bk[t] : bq[t - 32];

    #pragma unroll
    for (int j = 0; j < 8; ++j) {
        int idx = t + j * 256;
        int r = idx >> 5;
        int c = idx & 31;
        float4 v = ((const float4*)(features + (size_t)(node0 + r) * LATENT))[c];
        *(float4*)&sf[r * PAD + c * 4] = v;
    }
    __syncthreads();

    const int tx = t & 15;
    const int ty = t >> 4;

    float acc[4][4];
    #pragma unroll
    for (int i = 0; i < 4; ++i)
        #pragma unroll
        for (int u = 0; u < 4; ++u) acc[i][u] = 0.f;

    #pragma unroll 4
    for (int kk = 0; kk < 32; ++kk) {
        float4 a[4], b[4];
        #pragma unroll
        for (int i = 0; i < 4; ++i)
            a[i] = *(const float4*)&sf[(ty * 4 + i) * PAD + kk * 4];
        #pragma unroll
        for (int u = 0; u < 4; ++u)
            b[u] = *(const float4*)&sw[(tx + 16 * u) * PAD + kk * 4];
        #pragma unroll
        for (int i = 0; i < 4; ++i)
            #pragma unroll
            for (int u = 0; u < 4; ++u)
                acc[i][u] += a[i].x * b[u].x + a[i].y * b[u].y
                           + a[i].z * b[u].z + a[i].w * b[u].w;
    }

    #pragma unroll
    for (int u = 0; u < 4; ++u) {
        const int d = tx + 16 * u;
        const float bias = sb[d];
        __half* base = (d < 32) ? ks : qs;
        const int dd = d & 31;
        #pragma unroll
        for (int i = 0; i < 4; ++i) {
            const int node = node0 + ty * 4 + i;
            base[(size_t)node * DQK + dd] = __float2half(acc[i][u] + bias);
        }
    }
}

// ---------------------------------------------------------------------------
// Kernel 2: MFMA edge dots, deep-pipelined for MLP.
// Wave = EG groups x 16 edges. Phase 1: all 2*EG index loads. Phase 2: all
// 2*EG divergent gathers issued back-to-back (sched_barrier fences keep the
// compiler from sinking them to uses). Phase 3: EG MFMAs + writer stores.
// Gather layout: lane = (edge i = lane&15, k-chunk c = lane>>4, 8 f16/lane)
// == A/B fragment of mfma_f32_16x16x32_f16; wanted dots = diagonal C[i][i]
// (transpose-robust), at lane ((i>>2)<<4)|i, reg i&3.
// ---------------------------------------------------------------------------
__global__ __launch_bounds__(256, 2) void edge_kernel(
    const int* __restrict__ xidx,     // indices[1] flat
    const int* __restrict__ yidx,     // indices[2] flat
    const __half* __restrict__ ks,    // [B*N, 32] f16
    const __half* __restrict__ qs,
    float* __restrict__ out)          // [B*N*K]
{
    const int lane = threadIdx.x & 63;
    const int wave = (blockIdx.x * 256 + threadIdx.x) >> 6;
    const int i = lane & 15;          // edge within group
    const int c = lane >> 4;          // k-chunk (8 f16)
    const int e_base = wave * (16 * EG);
    const int b = e_base >> 20;       // batch (uniform; 128 | 2^20)
    const int nodebase = b << 14;     // b * NN

    const _Float16* ksh = (const _Float16*)ks;
    const _Float16* qsh = (const _Float16*)qs;

    // Phase 1: indices for all groups (lane i's edge in each group)
    int xs[EG], ys[EG];
    #pragma unroll
    for (int g = 0; g < EG; ++g) {
        xs[g] = xidx[e_base + g * 16 + i];
        ys[g] = yidx[e_base + g * 16 + i];
    }
    __builtin_amdgcn_sched_barrier(0);

    // Phase 2: all gathers in flight
    half8 kv[EG], qv[EG];
    #pragma unroll
    for (int g = 0; g < EG; ++g) {
        kv[g] = *(const half8*)(ksh + (((size_t)(nodebase + xs[g])) << 5) + (c << 3));
        qv[g] = *(const half8*)(qsh + (((size_t)(nodebase + ys[g])) << 5) + (c << 3));
    }
    __builtin_amdgcn_sched_barrier(0);

    // Phase 3: MFMA + diagonal extraction + store
    const bool writer = (c == (i >> 2));
    const int reg = i & 3;
    #pragma unroll
    for (int g = 0; g < EG; ++g) {
        f32x4 acc = {0.f, 0.f, 0.f, 0.f};
        acc = __builtin_amdgcn_mfma_f32_16x16x32_f16(kv[g], qv[g], acc, 0, 0, 0);
        float v = acc[0];
        v = (reg == 1) ? acc[1] : v;
        v = (reg == 2) ? acc[2] : v;
        v = (reg == 3) ? acc[3] : v;
        if (writer) out[e_base + g * 16 + i] = v * 0.17677669529663687f;
    }
}

// ---------------------------------------------------------------------------
extern "C" void kernel_launch(void* const* d_in, const int* in_sizes, int n_in,
                              void* d_out, int out_size, void* d_ws, size_t ws_size,
                              hipStream_t stream) {
    // Input order: indices, img, features, Wk, bk, Wq, bq
    const int*   indices  = (const int*)d_in[0];
    const float* features = (const float*)d_in[2];
    const float* Wk       = (const float*)d_in[3];
    const float* bk       = (const float*)d_in[4];
    const float* Wq       = (const float*)d_in[5];
    const float* bq       = (const float*)d_in[6];
    float* out = (float*)d_out;

    __half* ks = (__half*)d_ws;                       // [B*N, 32] f16
    __half* qs = ks + (size_t)TOTAL_NODES * DQK;

    const int* xidx = indices + (size_t)1 * TOTAL_EDGES;  // row 1 -> keys
    const int* yidx = indices + (size_t)2 * TOTAL_EDGES;  // row 2 -> queries

    proj_kernel<<<TOTAL_NODES / 64, 256, 0, stream>>>(features, Wk, bk, Wq, bq, ks, qs);
    // 4 waves x 128 edges per block
    edge_kernel<<<TOTAL_EDGES / 512, 256, 0, stream>>>(xidx, yidx, ks, qs, out);
}